// Round 11
// baseline (2336.415 us; speedup 1.0000x reference)
//
#include <hip/hip_runtime.h>
#include <math.h>

// ---------------------------------------------------------------------------
// Variance-propagating UNet (density prop), NHWC.
// Round-27: r26 (974us) + 2-WAVE BLOCKS. The r2-r10 invariant — D1B (18
// chunks, 89MB) == D1A (36 chunks, 319MB) == ~131us — means the big layers
// are bound by neither chunk latency nor bytes: they are GRID-STARVED
// (977 4-wave blocks = 3.8/CU nominal, 2.6 effective; BB = 1/CU). Blocks are
// now 2 waves x 32 px (128 thr): block count doubles everywhere (D1A 1954 =
// 7.6/CU, BB 512 = 2/CU), giving the scheduler 2-3x more independent
// latency chains to overlap the per-chunk barrier drains. LDS tile/chunk
// structure unchanged; each thread stages 6 uint4s (was 3). Accumulation
// order per output pixel is BITWISE IDENTICAL (numerics fence from r25
// respected). Fused q9, batched prep, XCD swizzle kept from r26.
// ---------------------------------------------------------------------------

typedef __attribute__((ext_vector_type(8))) short short8;
typedef __attribute__((ext_vector_type(4))) float floatx4;

__device__ __forceinline__ float softplus_f(float x) { return log1pf(expf(x)); }

__device__ __forceinline__ unsigned short f2bf(float x) {
    unsigned int u = __float_as_uint(x);
    u = (u + 0x7FFF + ((u >> 16) & 1)) >> 16;
    return (unsigned short)u;
}
__device__ __forceinline__ float bfval(unsigned short h) {
    return __uint_as_float((unsigned int)h << 16);
}

// ---- batched weight prep: all 11 layers in one launch ----
struct WMeta {
    const float* w[12];
    const float* wsig[12];
    int woff_[12];    // cumulative element start per layer
    int spoff_[12];   // cumulative cout start per layer
    int cin_[12];
    int cout_[12];
    int nlayers;
    int totalW;
    int totalSp;
};

__global__ void wprep_all_kernel(WMeta m,
                                 unsigned short* __restrict__ wTh,
                                 unsigned short* __restrict__ wTl,
                                 unsigned short* __restrict__ wTsq,
                                 float* __restrict__ spb)
{
    int idx = blockIdx.x * blockDim.x + threadIdx.x;
    if (idx < m.totalW) {
        int l = 0;
        while (l + 1 < m.nlayers && idx >= m.woff_[l + 1]) l++;
        int local = idx - m.woff_[l];
        int Cin = m.cin_[l], Cout = m.cout_[l];
        int per = Cin * Cout;
        int tap = local / per;
        int rem = local - tap * per;
        int co = rem / Cin;
        int ci = rem - co * Cin;
        float v = m.w[l][(size_t)(tap * Cin + ci) * Cout + co];
        unsigned short hh = f2bf(v);
        wTh[idx] = hh;
        wTl[idx] = f2bf(v - bfval(hh));
        wTsq[idx] = f2bf(v * v);
    } else if (idx < m.totalW + m.totalSp) {
        int j = idx - m.totalW;
        int l = 0;
        while (l + 1 < m.nlayers && j >= m.spoff_[l + 1]) l++;
        spb[j] = softplus_f(m.wsig[l][j - m.spoff_[l]]);
    }
}

// ---- FUSED MFMA layer: mu (4-MFMA split) + s (2-MFMA hi/lo) + q9 in-kernel
// + relu gate. Each block: 2 waves x 16 px x 64 cout. Weight tile staged in
// LDS (coalesced, shared by 2 waves), stride 36; reg-prefetched one chunk
// ahead. q9 accumulated from A fragments, quad-reduced via shfl_xor.
// unpoolMode: tap validity by parity.
__global__ void __launch_bounds__(128)
fused_layer_kernel(const unsigned short* __restrict__ m1h, const unsigned short* __restrict__ m1l,
                   const unsigned short* __restrict__ s1h, const unsigned short* __restrict__ s1l,
                   const unsigned short* __restrict__ m2h, const unsigned short* __restrict__ m2l,
                   const unsigned short* __restrict__ s2h, const unsigned short* __restrict__ s2l,
                   const unsigned short* __restrict__ wTh, const unsigned short* __restrict__ wTl,
                   const unsigned short* __restrict__ wTsq,
                   const float* __restrict__ spv_,
                   float* __restrict__ oMf, float* __restrict__ oSf,
                   unsigned short* __restrict__ oMh, unsigned short* __restrict__ oMl,
                   unsigned short* __restrict__ oSh, unsigned short* __restrict__ oSl,
                   int B_, int H, int W, int Hin, int Win, int unpoolMode,
                   int Cin1, int Cin2,
                   int H2, int W2, int dh, int dw, int Cout)
{
    __shared__ unsigned short ldsB[3 * 2304];   // 3 arrays x 64 co x 36 (32+4 pad)
    const int tid = threadIdx.x;
    const int lane = tid & 63;
    const int wave = tid >> 6;                  // 0..1
    const int total = B_ * H * W;
    const int Cin = Cin1 + Cin2;
    const int ntiles = Cout >> 6;
    const int nPixBlk = (total + 31) >> 5;      // 32 px per block
    const int nReal = nPixBlk * ntiles;
    const int chunk = (int)gridDim.x >> 3;
    int gid = ((int)blockIdx.x & 7) * chunk + ((int)blockIdx.x >> 3);
    if (gid >= nReal) return;                   // block-uniform: barrier-safe
    const int coTile = gid % ntiles;
    const int pixBlk = gid / ntiles;
    const int pixBase = pixBlk * 32 + wave * 16;
    const int coBase = coTile * 64;
    const int row = lane & 15;
    const int quad = lane >> 4;

    // ---- per-thread staging constants (u = j*128 + tid over 3x64x4 uint4s) ----
    const unsigned short* wsel[6];
    int tofs[6], ldso[6];
#pragma unroll
    for (int j = 0; j < 6; j++) {
        int u = j * 128 + tid;
        int arr = u >> 8, rem = u & 255, co = rem >> 2, part = rem & 3;
        wsel[j] = (arr == 0) ? wTh : (arr == 1) ? wTl : wTsq;
        tofs[j] = co * Cin + part * 8;
        ldso[j] = arr * 2304 + co * 36 + part * 8;
    }

    int P = pixBase + row;
    bool pv = P < total;
    int Pc = pv ? P : 0;
    int pb = Pc / (H * W);
    int r0i = Pc - pb * (H * W);
    int ph = r0i / W;
    int pw = r0i - ph * W;

    floatx4 accM[4], accS[4];
#pragma unroll
    for (int i = 0; i < 4; i++) {
        accM[i] = (floatx4){0.f, 0.f, 0.f, 0.f};
        accS[i] = (floatx4){0.f, 0.f, 0.f, 0.f};
    }
    const short8 zero8 = {0, 0, 0, 0, 0, 0, 0, 0};
    float qacc = 0.f;                           // q9 partial: this lane's quad slices

    const size_t tapstep = (size_t)Cout * Cin;
    size_t tapbase = (size_t)coBase * Cin;      // (tap*Cout + coBase)*Cin, tap=0

    // ---- prefetch chunk 0 (tap 0, col 0) into regs ----
    uint4 pf[6];
#pragma unroll
    for (int j = 0; j < 6; j++) pf[j] = *(const uint4*)(wsel[j] + tapbase + tofs[j]);

    for (int tap = 0; tap < 9; tap++, tapbase += tapstep) {
        int kh = tap / 3, kw = tap - kh * 3;
        int ih, iw;
        bool tv;
        if (unpoolMode) {
            int uh = ph + kh, uw = pw + kw;
            tv = pv && (uh & 1) && (uw & 1);
            ih = (uh - 1) >> 1;
            iw = (uw - 1) >> 1;
        } else {
            ih = ph + kh - 1;
            iw = pw + kw - 1;
            tv = pv && ((unsigned)ih < (unsigned)Hin) && ((unsigned)iw < (unsigned)Win);
        }
        if (!tv) { ih = 0; iw = 0; }
        const int nsrc = (Cin2 > 0) ? 2 : 1;
        for (int src = 0; src < nsrc; src++) {
            const int csrc = src ? Cin2 : Cin1;
            const int cofs = src ? Cin1 : 0;
            const unsigned short* aMhp = src ? m2h : m1h;
            const unsigned short* aMlp = src ? m2l : m1l;
            const unsigned short* aShp = src ? s2h : s1h;
            const unsigned short* aSlp = src ? s2l : s1l;
            size_t ab;
            if (src) ab = ((size_t)(pb * H2 + ih + dh) * W2 + (iw + dw)) * (size_t)Cin2 + quad * 8;
            else     ab = ((size_t)(pb * Hin + ih) * Win + iw) * (size_t)Cin1 + quad * 8;
            for (int kb = 0; kb < csrc; kb += 32) {
                __syncthreads();
                // ---- commit staged regs to LDS (cheap; no global latency here) ----
#pragma unroll
                for (int j = 0; j < 6; j++) *(uint4*)(&ldsB[ldso[j]]) = pf[j];
                __syncthreads();
                // ---- A fragments (per-lane) — issue first, on critical path ----
                short8 aMh = zero8, aMl = zero8, aSh = zero8, aSl = zero8;
                if (tv) {
                    aMh = *(const short8*)(aMhp + ab + kb);
                    aMl = *(const short8*)(aMlp + ab + kb);
                    aSh = *(const short8*)(aShp + ab + kb);
                    aSl = *(const short8*)(aSlp + ab + kb);
                    // ---- q9 accumulation from the loaded fragments ----
#pragma unroll
                    for (int e = 0; e < 8; e++) {
                        float m = bfval((unsigned short)aMh[e]) + bfval((unsigned short)aMl[e]);
                        qacc += m * m
                              + bfval((unsigned short)aSh[e]) + bfval((unsigned short)aSl[e]);
                    }
                }
                // ---- prefetch NEXT chunk's weight tile (latency hides under MFMA) ----
                {
                    int ncol = cofs + kb + 32;
                    size_t nbase;
                    bool hn;
                    if (ncol < Cin) { nbase = tapbase + ncol; hn = true; }
                    else            { nbase = tapbase + tapstep; hn = (tap < 8); }
                    if (hn) {
#pragma unroll
                        for (int j = 0; j < 6; j++)
                            pf[j] = *(const uint4*)(wsel[j] + nbase + tofs[j]);
                    }
                }
#pragma unroll
                for (int nt = 0; nt < 4; nt++) {
                    int lo = (nt * 16 + row) * 36 + quad * 8;
                    short8 bh = *(const short8*)(&ldsB[lo]);
                    short8 bl = *(const short8*)(&ldsB[2304 + lo]);
                    short8 bq = *(const short8*)(&ldsB[4608 + lo]);
                    accM[nt] = __builtin_amdgcn_mfma_f32_16x16x32_bf16(aMh, bh, accM[nt], 0, 0, 0);
                    accM[nt] = __builtin_amdgcn_mfma_f32_16x16x32_bf16(aMl, bh, accM[nt], 0, 0, 0);
                    accM[nt] = __builtin_amdgcn_mfma_f32_16x16x32_bf16(aMh, bl, accM[nt], 0, 0, 0);
                    accM[nt] = __builtin_amdgcn_mfma_f32_16x16x32_bf16(aMl, bl, accM[nt], 0, 0, 0);
                    accS[nt] = __builtin_amdgcn_mfma_f32_16x16x32_bf16(aSh, bq, accS[nt], 0, 0, 0);
                    accS[nt] = __builtin_amdgcn_mfma_f32_16x16x32_bf16(aSl, bq, accS[nt], 0, 0, 0);
                }
            }
        }
    }

    // ---- finish q9: reduce across the 4 quads (lanes row, row+16, +32, +48) ----
    qacc += __shfl_xor(qacc, 16);
    qacc += __shfl_xor(qacc, 32);
    // every lane now holds q9 for pixel pixBase + (lane & 15)

#pragma unroll
    for (int nt = 0; nt < 4; nt++) {
        int co = coBase + nt * 16 + row;
        float spv = spv_[co];
        floatx4 am = accM[nt];
        floatx4 as = accS[nt];
#pragma unroll
        for (int r = 0; r < 4; r++) {
            int P2 = pixBase + quad * 4 + r;
            float qv = __shfl(qacc, quad * 4 + r);   // q9[P2] from lane quad*4+r
            if (P2 < total) {
                size_t o = (size_t)P2 * Cout + co;
                float mu = am[r];
                float s = qv * spv + as[r];
                if (!(mu > 0.f)) { mu = 0.f; s = 0.f; }
                if (oMf) oMf[o] = mu;
                if (oSf) oSf[o] = s;
                if (oMh) {
                    unsigned short mh = f2bf(mu);
                    oMh[o] = mh;
                    oMl[o] = f2bf(mu - bfval(mh));
                    unsigned short sh = f2bf(s);
                    oSh[o] = sh;
                    oSl[o] = f2bf(s - bfval(sh));
                }
            }
        }
    }
}

// ---- first layer (Cin=3): hi/lo outputs
__global__ void conv_input_relu_kernel(const float* __restrict__ x,
                                       const float* __restrict__ w_mu,
                                       const float* __restrict__ w_sig,
                                       unsigned short* __restrict__ m_h,
                                       unsigned short* __restrict__ m_l,
                                       unsigned short* __restrict__ s_h,
                                       unsigned short* __restrict__ s_l,
                                       int B_, int H, int W, int Cin, int Cout)
{
    int co = threadIdx.x;
    int pix = blockIdx.x * blockDim.y + threadIdx.y;
    int total = B_ * H * W;
    if (pix >= total) return;
    int b = pix / (H * W);
    int rem = pix % (H * W);
    int h = rem / W, w = rem % W;

    float mu = 0.f, q = 0.f;
    for (int kh = 0; kh < 3; kh++) {
        int ih = h + kh - 1;
        if (ih < 0 || ih >= H) continue;
        for (int kw = 0; kw < 3; kw++) {
            int iw = w + kw - 1;
            if (iw < 0 || iw >= W) continue;
            const float* xp = x + ((size_t)(b * H + ih) * W + iw) * Cin;
            const float* wp = w_mu + (size_t)((kh * 3 + kw) * Cin) * Cout + co;
            for (int ci = 0; ci < Cin; ci++) {
                float xv = xp[ci];
                mu += xv * wp[(size_t)ci * Cout];
                q += xv * xv;
            }
        }
    }
    float s = q * softplus_f(w_sig[co]);
    if (!(mu > 0.f)) { mu = 0.f; s = 0.f; }
    size_t oidx = (size_t)pix * Cout + co;
    unsigned short mh = f2bf(mu);
    m_h[oidx] = mh;
    m_l[oidx] = f2bf(mu - bfval(mh));
    unsigned short sh = f2bf(s);
    s_h[oidx] = sh;
    s_l[oidx] = f2bf(s - bfval(sh));
}

// ---- pool: fp32 mu for argmax; outputs hi/lo mu + gathered hi/lo s
__global__ void pool_kernel(const float* __restrict__ mu_in,
                            const unsigned short* __restrict__ s_h,
                            const unsigned short* __restrict__ s_l,
                            unsigned short* __restrict__ pm_h,
                            unsigned short* __restrict__ pm_l,
                            unsigned short* __restrict__ ps_h,
                            unsigned short* __restrict__ ps_l,
                            int B_, int H, int W, int C)
{
    int Ho = H / 2, Wo = W / 2;
    size_t total = (size_t)B_ * Ho * Wo * C;
    size_t idx = (size_t)blockIdx.x * blockDim.x + threadIdx.x;
    if (idx >= total) return;
    int c = idx % C;
    size_t t = idx / C;
    int w = t % Wo; t /= Wo;
    int h = t % Ho;
    int b = t / Ho;
    size_t i0 = ((size_t)(b * H + 2 * h) * W + 2 * w) * C + c;
    size_t rowStride = (size_t)W * C;
    float m00 = mu_in[i0], m01 = mu_in[i0 + C];
    float m10 = mu_in[i0 + rowStride], m11 = mu_in[i0 + rowStride + C];
    int best = 0; float bm = m00;
    if (m01 > bm) { bm = m01; best = 1; }
    if (m10 > bm) { bm = m10; best = 2; }
    if (m11 > bm) { bm = m11; best = 3; }
    size_t off = (size_t)(best >> 1) * rowStride + (size_t)(best & 1) * C;
    unsigned short mh = f2bf(bm);
    pm_h[idx] = mh;
    pm_l[idx] = f2bf(bm - bfval(mh));
    ps_h[idx] = s_h[i0 + off];
    ps_l[idx] = s_l[i0 + off];
}

// ---- final 1x1 conv_inter + C=2 softmax density prop (fp32 in)
__global__ void final_kernel(const float* __restrict__ mu_in,
                             const float* __restrict__ s_in,
                             const float* __restrict__ w_mu,
                             const float* __restrict__ w_sig,
                             float* __restrict__ out,
                             int B_, int H, int W, int Cin)
{
    int pix = blockIdx.x * blockDim.x + threadIdx.x;
    int total = B_ * H * W;
    if (pix >= total) return;
    const float* mp = mu_in + (size_t)pix * Cin;
    const float* sp = s_in + (size_t)pix * Cin;
    float mu0 = 0.f, mu1 = 0.f, s0a = 0.f, s1a = 0.f, q = 0.f;
    for (int ci = 0; ci < Cin; ci += 4) {
        float4 m = *(const float4*)(mp + ci);
        float4 s = *(const float4*)(sp + ci);
        float4 wa = *(const float4*)(w_mu + ci * 2);
        float4 wb = *(const float4*)(w_mu + ci * 2 + 4);
        mu0 += m.x * wa.x + m.y * wa.z + m.z * wb.x + m.w * wb.z;
        mu1 += m.x * wa.y + m.y * wa.w + m.z * wb.y + m.w * wb.w;
        s0a += s.x * (wa.x * wa.x) + s.y * (wa.z * wa.z) + s.z * (wb.x * wb.x) + s.w * (wb.z * wb.z);
        s1a += s.x * (wa.y * wa.y) + s.y * (wa.w * wa.w) + s.z * (wb.y * wb.y) + s.w * (wb.w * wb.w);
        q += m.x * m.x + s.x + m.y * m.y + s.y + m.z * m.z + s.z + m.w * m.w + s.w;
    }
    float s0 = q * softplus_f(w_sig[0]) + s0a;
    float s1 = q * softplus_f(w_sig[1]) + s1a;
    float mx = fmaxf(mu0, mu1);
    float e0 = expf(mu0 - mx), e1 = expf(mu1 - mx);
    float inv = 1.f / (e0 + e1);
    float p0 = e0 * inv, p1 = e1 * inv;
    float g00 = p0 - p0 * p0, g01 = -p0 * p1;
    float g10 = -p1 * p0,     g11 = p1 - p1 * p1;
    float so0 = g00 * g00 * s0 + g01 * g01 * s1;
    float so1 = g10 * g10 * s0 + g11 * g11 * s1;
    out[(size_t)pix * 2]     = p0;
    out[(size_t)pix * 2 + 1] = p1;
    size_t off = (size_t)total * 2;
    out[off + (size_t)pix * 2]     = so0;
    out[off + (size_t)pix * 2 + 1] = so1;
}

// ---------------------------------------------------------------------------

extern "C" void kernel_launch(void* const* d_in, const int* in_sizes, int n_in,
                              void* d_out, int out_size, void* d_ws, size_t ws_size,
                              hipStream_t stream)
{
    const float* x = (const float*)d_in[0];
    enum { E1A, E1B, E2A, E2B, BA, BB, D2U, D2A, D2B, D1U, D1A, D1B, FIN, NW };
    const float* wmu[NW];
    const float* wsig[NW];
    for (int i = 0; i < NW; i++) {
        wmu[i]  = (const float*)d_in[1 + 2 * i];
        wsig[i] = (const float*)d_in[2 + 2 * i];
    }

    const int B_ = 4;
    float* ws = (float*)d_ws;
    float* M0  = ws;                         // 4194304 fp32 mu scratch
    float* SF  = ws + 4194304;               // 4194304 fp32 s scratch
    float* spb = ws + 8519680;               // 2048
    unsigned short* us = (unsigned short*)(ws + 8521728);
    const size_t NB = 4194304;
    unsigned short* aMh = us;                // A set
    unsigned short* aMl = us + NB;
    unsigned short* aSh = us + 2 * NB;
    unsigned short* aSl = us + 3 * NB;
    unsigned short* bMh = us + 4 * NB;       // B set
    unsigned short* bMl = us + 5 * NB;
    unsigned short* bSh = us + 6 * NB;
    unsigned short* bSl = us + 7 * NB;
    unsigned short* e1Mh = us + 8 * NB;      // E1 skip
    unsigned short* e1Ml = us + 9 * NB;
    unsigned short* e1Sh = us + 10 * NB;
    unsigned short* e1Sl = us + 11 * NB;
    unsigned short* e2Mh = us + 12 * NB;     // E2 skip (2097152 each)
    unsigned short* e2Ml = e2Mh + 2097152;
    unsigned short* e2Sh = e2Ml + 2097152;
    unsigned short* e2Sl = e2Sh + 2097152;
    unsigned short* wTh  = e2Sl + 2097152;   // 2064384 each (11 layers)
    unsigned short* wTl  = wTh + 2064384;
    unsigned short* wTsq = wTl + 2064384;

    // all 11 conv layers on MFMA
    const int mlay[11]  = {E1B, E2A, E2B, BA, BB, D2U, D2A, D2B, D1U, D1A, D1B};
    const int mcin[11]  = {64, 64, 128, 128, 256, 256, 256, 128, 128, 128, 64};
    const int mcout[11] = {64, 128, 128, 256, 256, 128, 128, 128, 64, 64, 64};
    size_t woff[NW]; int spoff[NW];
    {
        WMeta meta;
        int wo = 0, so = 0;
        for (int i = 0; i < 11; i++) {
            int l = mlay[i];
            woff[l] = (size_t)wo; spoff[l] = so;
            meta.w[i] = wmu[l];
            meta.wsig[i] = wsig[l];
            meta.woff_[i] = wo;
            meta.spoff_[i] = so;
            meta.cin_[i] = mcin[i];
            meta.cout_[i] = mcout[i];
            wo += 9 * mcin[i] * mcout[i];
            so += mcout[i];
        }
        meta.nlayers = 11;
        meta.totalW = wo;        // 2064384
        meta.totalSp = so;       // 1344
        int n = wo + so;
        wprep_all_kernel<<<dim3((n + 255) / 256), dim3(256), 0, stream>>>(
            meta, wTh, wTl, wTsq, spb);
    }

    // dense fused MFMA layer (q9 computed in-kernel; 2-wave blocks)
    auto flayer = [&](const unsigned short* i_mh, const unsigned short* i_ml,
                      const unsigned short* i_sh, const unsigned short* i_sl, int ci1,
                      const unsigned short* k_mh, const unsigned short* k_ml,
                      const unsigned short* k_sh, const unsigned short* k_sl,
                      int ci2, int h2, int w2, int dh, int dw,
                      int H, int W, int widx, int cout,
                      float* oMf, float* oSf,
                      unsigned short* oMh, unsigned short* oMl,
                      unsigned short* oSh, unsigned short* oSl) {
        int total = B_ * H * W;
        int nReal = ((total + 31) / 32) * (cout / 64);
        int G = ((nReal + 7) / 8) * 8;
        fused_layer_kernel<<<dim3(G), dim3(128), 0, stream>>>(
            i_mh, i_ml, i_sh, i_sl, k_mh, k_ml, k_sh, k_sl,
            wTh + woff[widx], wTl + woff[widx], wTsq + woff[widx], spb + spoff[widx],
            oMf, oSf, oMh, oMl, oSh, oSl,
            B_, H, W, H, W, 0, ci1, ci2, h2, w2, dh, dw, cout);
    };

    // unpool fused MFMA layer: input [Hin,Win,ci] -> out [2Hin-1, 2Win-1, cout]
    auto ulayer = [&](const unsigned short* i_mh, const unsigned short* i_ml,
                      const unsigned short* i_sh, const unsigned short* i_sl, int ci,
                      int Hin, int Win, int widx, int cout,
                      unsigned short* oMh, unsigned short* oMl,
                      unsigned short* oSh, unsigned short* oSl) {
        int Hout = 2 * Hin - 1, Wout = 2 * Win - 1;
        int total = B_ * Hout * Wout;
        int nReal = ((total + 31) / 32) * (cout / 64);
        int G = ((nReal + 7) / 8) * 8;
        fused_layer_kernel<<<dim3(G), dim3(128), 0, stream>>>(
            i_mh, i_ml, i_sh, i_sl, nullptr, nullptr, nullptr, nullptr,
            wTh + woff[widx], wTl + woff[widx], wTsq + woff[widx], spb + spoff[widx],
            nullptr, nullptr, oMh, oMl, oSh, oSl,
            B_, Hout, Wout, Hin, Win, 1, ci, 0, 0, 0, 0, 0, cout);
    };

    // ---- encoder level 1 ----
    {
        int totalPix = B_ * 128 * 128;
        conv_input_relu_kernel<<<dim3((totalPix + 3) / 4), dim3(64, 4), 0, stream>>>(
            x, wmu[E1A], wsig[E1A], aMh, aMl, aSh, aSl, B_, 128, 128, 3, 64);
    }
    // E1B: A -> E1 skip (hi/lo) + fp32 mu (M0) for pool argmax
    flayer(aMh, aMl, aSh, aSl, 64, nullptr, nullptr, nullptr, nullptr, 0, 0, 0, 0, 0,
           128, 128, E1B, 64, M0, nullptr, e1Mh, e1Ml, e1Sh, e1Sl);
    {
        size_t total = (size_t)B_ * 64 * 64 * 64;
        pool_kernel<<<dim3((total + 255) / 256), dim3(256), 0, stream>>>(
            M0, e1Sh, e1Sl, bMh, bMl, bSh, bSl, B_, 128, 128, 64);
    }
    // ---- encoder level 2 ----
    flayer(bMh, bMl, bSh, bSl, 64, nullptr, nullptr, nullptr, nullptr, 0, 0, 0, 0, 0,
           64, 64, E2A, 128, nullptr, nullptr, aMh, aMl, aSh, aSl);
    flayer(aMh, aMl, aSh, aSl, 128, nullptr, nullptr, nullptr, nullptr, 0, 0, 0, 0, 0,
           64, 64, E2B, 128, M0, nullptr, e2Mh, e2Ml, e2Sh, e2Sl);
    {
        size_t total = (size_t)B_ * 32 * 32 * 128;
        pool_kernel<<<dim3((total + 255) / 256), dim3(256), 0, stream>>>(
            M0, e2Sh, e2Sl, bMh, bMl, bSh, bSl, B_, 64, 64, 128);
    }
    // ---- bottleneck ----
    flayer(bMh, bMl, bSh, bSl, 128, nullptr, nullptr, nullptr, nullptr, 0, 0, 0, 0, 0,
           32, 32, BA, 256, nullptr, nullptr, aMh, aMl, aSh, aSl);
    flayer(aMh, aMl, aSh, aSl, 256, nullptr, nullptr, nullptr, nullptr, 0, 0, 0, 0, 0,
           32, 32, BB, 256, nullptr, nullptr, bMh, bMl, bSh, bSl);
    // ---- decoder level 2 (unpool conv on MFMA, 4-term gates) ----
    ulayer(bMh, bMl, bSh, bSl, 256, 32, 32, D2U, 128, aMh, aMl, aSh, aSl);
    flayer(aMh, aMl, aSh, aSl, 128, e2Mh, e2Ml, e2Sh, e2Sl, 128, 64, 64, 0, 0,
           63, 63, D2A, 128, nullptr, nullptr, bMh, bMl, bSh, bSl);
    flayer(bMh, bMl, bSh, bSl, 128, nullptr, nullptr, nullptr, nullptr, 0, 0, 0, 0, 0,
           63, 63, D2B, 128, nullptr, nullptr, aMh, aMl, aSh, aSl);
    // ---- decoder level 1 (unpool conv on MFMA, 4-term gates) ----
    ulayer(aMh, aMl, aSh, aSl, 128, 63, 63, D1U, 64, bMh, bMl, bSh, bSl);
    flayer(bMh, bMl, bSh, bSl, 64, e1Mh, e1Ml, e1Sh, e1Sl, 64, 128, 128, 1, 1,
           125, 125, D1A, 64, nullptr, nullptr, aMh, aMl, aSh, aSl);
    flayer(aMh, aMl, aSh, aSl, 64, nullptr, nullptr, nullptr, nullptr, 0, 0, 0, 0, 0,
           125, 125, D1B, 64, M0, SF, nullptr, nullptr, nullptr, nullptr);
    // ---- final 1x1 + softmax prop ----
    {
        int totalPix = B_ * 125 * 125;
        final_kernel<<<dim3((totalPix + 63) / 64), dim3(64), 0, stream>>>(
            M0, SF, wmu[FIN], wsig[FIN], (float*)d_out, B_, 125, 125, 64);
    }
}

// Round 13
// 964.975 us; speedup vs baseline: 2.4212x; 2.4212x over previous
//
#include <hip/hip_runtime.h>
#include <math.h>

// ---------------------------------------------------------------------------
// Variance-propagating UNet (density prop), NHWC.
// Round-28 RESUBMIT (previous round failed on container infra, not kernel).
// r26/r10 restored EXACTLY (974us best; r27's 2-wave blocks quadrupled HBM
// traffic -> 2336us, reverted) + PARITY-CLASSED UNPOOL. In unpool mode only
// ~2.25 of 9 taps are parity-valid per pixel, but raster-strip waves mix
// parities so every chunk ran (MFMA on zeros). New fused_unpool_kernel
// groups each block's 64 px by parity class (h&1,w&1): tap validity becomes
// block-uniform -> class (0,0) runs 1 tap, (0,1)/(1,0) 2, (1,1) 4. Skipped
// taps contributed exact +0 before, and valid taps keep ascending order ->
// per-pixel accumulation is bitwise preserved (r25 numerics fence).
// D2U chunks 72 -> 8/16/32 by class, D1U 36 -> 4/8/16. Dense kernel, pools,
// prep, final: byte-for-byte r26.
// ---------------------------------------------------------------------------

typedef __attribute__((ext_vector_type(8))) short short8;
typedef __attribute__((ext_vector_type(4))) float floatx4;

__device__ __forceinline__ float softplus_f(float x) { return log1pf(expf(x)); }

__device__ __forceinline__ unsigned short f2bf(float x) {
    unsigned int u = __float_as_uint(x);
    u = (u + 0x7FFF + ((u >> 16) & 1)) >> 16;
    return (unsigned short)u;
}
__device__ __forceinline__ float bfval(unsigned short h) {
    return __uint_as_float((unsigned int)h << 16);
}

// ---- batched weight prep: all 11 layers in one launch ----
struct WMeta {
    const float* w[12];
    const float* wsig[12];
    int woff_[12];    // cumulative element start per layer
    int spoff_[12];   // cumulative cout start per layer
    int cin_[12];
    int cout_[12];
    int nlayers;
    int totalW;
    int totalSp;
};

__global__ void wprep_all_kernel(WMeta m,
                                 unsigned short* __restrict__ wTh,
                                 unsigned short* __restrict__ wTl,
                                 unsigned short* __restrict__ wTsq,
                                 float* __restrict__ spb)
{
    int idx = blockIdx.x * blockDim.x + threadIdx.x;
    if (idx < m.totalW) {
        int l = 0;
        while (l + 1 < m.nlayers && idx >= m.woff_[l + 1]) l++;
        int local = idx - m.woff_[l];
        int Cin = m.cin_[l], Cout = m.cout_[l];
        int per = Cin * Cout;
        int tap = local / per;
        int rem = local - tap * per;
        int co = rem / Cin;
        int ci = rem - co * Cin;
        float v = m.w[l][(size_t)(tap * Cin + ci) * Cout + co];
        unsigned short hh = f2bf(v);
        wTh[idx] = hh;
        wTl[idx] = f2bf(v - bfval(hh));
        wTsq[idx] = f2bf(v * v);
    } else if (idx < m.totalW + m.totalSp) {
        int j = idx - m.totalW;
        int l = 0;
        while (l + 1 < m.nlayers && j >= m.spoff_[l + 1]) l++;
        spb[j] = softplus_f(m.wsig[l][j - m.spoff_[l]]);
    }
}

// ---- FUSED MFMA layer (dense): mu (4-MFMA split) + s (2-MFMA hi/lo) + q9
// in-kernel + relu gate. Each wave: 16 px x 64 cout. Weight tile staged in
// LDS (stride 36), reg-prefetched one chunk ahead. q9 via shfl_xor.
__global__ void __launch_bounds__(256)
fused_layer_kernel(const unsigned short* __restrict__ m1h, const unsigned short* __restrict__ m1l,
                   const unsigned short* __restrict__ s1h, const unsigned short* __restrict__ s1l,
                   const unsigned short* __restrict__ m2h, const unsigned short* __restrict__ m2l,
                   const unsigned short* __restrict__ s2h, const unsigned short* __restrict__ s2l,
                   const unsigned short* __restrict__ wTh, const unsigned short* __restrict__ wTl,
                   const unsigned short* __restrict__ wTsq,
                   const float* __restrict__ spv_,
                   float* __restrict__ oMf, float* __restrict__ oSf,
                   unsigned short* __restrict__ oMh, unsigned short* __restrict__ oMl,
                   unsigned short* __restrict__ oSh, unsigned short* __restrict__ oSl,
                   int B_, int H, int W, int Hin, int Win, int unpoolMode,
                   int Cin1, int Cin2,
                   int H2, int W2, int dh, int dw, int Cout)
{
    __shared__ unsigned short ldsB[3 * 2304];   // 3 arrays x 64 co x 36 (32+4 pad)
    const int tid = threadIdx.x;
    const int lane = tid & 63;
    const int wave = tid >> 6;
    const int total = B_ * H * W;
    const int Cin = Cin1 + Cin2;
    const int ntiles = Cout >> 6;
    const int nPixBlk = (total + 63) >> 6;
    const int nReal = nPixBlk * ntiles;
    const int chunk = (int)gridDim.x >> 3;
    int gid = ((int)blockIdx.x & 7) * chunk + ((int)blockIdx.x >> 3);
    if (gid >= nReal) return;                   // block-uniform: barrier-safe
    const int coTile = gid % ntiles;
    const int pixBlk = gid / ntiles;
    const int pixBase = pixBlk * 64 + wave * 16;
    const int coBase = coTile * 64;
    const int row = lane & 15;
    const int quad = lane >> 4;

    // ---- per-thread staging constants (u = tid*3 + j over 3x64x4 uint4s) ----
    const unsigned short* wsel0; const unsigned short* wsel1; const unsigned short* wsel2;
    int tofs0, tofs1, tofs2;     // co*Cin + part*8 (offset within a tap tile)
    int ldso0, ldso1, ldso2;     // LDS short offset for the ds_write
    {
        int u = tid * 3;
        int arr = u >> 8, rem = u & 255, co = rem >> 2, part = rem & 3;
        wsel0 = (arr == 0) ? wTh : (arr == 1) ? wTl : wTsq;
        tofs0 = co * Cin + part * 8;
        ldso0 = arr * 2304 + co * 36 + part * 8;
        u++;
        arr = u >> 8; rem = u & 255; co = rem >> 2; part = rem & 3;
        wsel1 = (arr == 0) ? wTh : (arr == 1) ? wTl : wTsq;
        tofs1 = co * Cin + part * 8;
        ldso1 = arr * 2304 + co * 36 + part * 8;
        u++;
        arr = u >> 8; rem = u & 255; co = rem >> 2; part = rem & 3;
        wsel2 = (arr == 0) ? wTh : (arr == 1) ? wTl : wTsq;
        tofs2 = co * Cin + part * 8;
        ldso2 = arr * 2304 + co * 36 + part * 8;
    }

    int P = pixBase + row;
    bool pv = P < total;
    int Pc = pv ? P : 0;
    int pb = Pc / (H * W);
    int r0i = Pc - pb * (H * W);
    int ph = r0i / W;
    int pw = r0i - ph * W;

    floatx4 accM[4], accS[4];
#pragma unroll
    for (int i = 0; i < 4; i++) {
        accM[i] = (floatx4){0.f, 0.f, 0.f, 0.f};
        accS[i] = (floatx4){0.f, 0.f, 0.f, 0.f};
    }
    const short8 zero8 = {0, 0, 0, 0, 0, 0, 0, 0};
    float qacc = 0.f;                           // q9 partial: this lane's quad slices

    const size_t tapstep = (size_t)Cout * Cin;
    size_t tapbase = (size_t)coBase * Cin;      // (tap*Cout + coBase)*Cin, tap=0

    // ---- prefetch chunk 0 (tap 0, col 0) into regs ----
    uint4 pf0 = *(const uint4*)(wsel0 + tapbase + tofs0);
    uint4 pf1 = *(const uint4*)(wsel1 + tapbase + tofs1);
    uint4 pf2 = *(const uint4*)(wsel2 + tapbase + tofs2);

    for (int tap = 0; tap < 9; tap++, tapbase += tapstep) {
        int kh = tap / 3, kw = tap - kh * 3;
        int ih, iw;
        bool tv;
        if (unpoolMode) {
            int uh = ph + kh, uw = pw + kw;
            tv = pv && (uh & 1) && (uw & 1);
            ih = (uh - 1) >> 1;
            iw = (uw - 1) >> 1;
        } else {
            ih = ph + kh - 1;
            iw = pw + kw - 1;
            tv = pv && ((unsigned)ih < (unsigned)Hin) && ((unsigned)iw < (unsigned)Win);
        }
        if (!tv) { ih = 0; iw = 0; }
        const int nsrc = (Cin2 > 0) ? 2 : 1;
        for (int src = 0; src < nsrc; src++) {
            const int csrc = src ? Cin2 : Cin1;
            const int cofs = src ? Cin1 : 0;
            const unsigned short* aMhp = src ? m2h : m1h;
            const unsigned short* aMlp = src ? m2l : m1l;
            const unsigned short* aShp = src ? s2h : s1h;
            const unsigned short* aSlp = src ? s2l : s1l;
            size_t ab;
            if (src) ab = ((size_t)(pb * H2 + ih + dh) * W2 + (iw + dw)) * (size_t)Cin2 + quad * 8;
            else     ab = ((size_t)(pb * Hin + ih) * Win + iw) * (size_t)Cin1 + quad * 8;
            for (int kb = 0; kb < csrc; kb += 32) {
                __syncthreads();
                // ---- commit staged regs to LDS (cheap; no global latency here) ----
                *(uint4*)(&ldsB[ldso0]) = pf0;
                *(uint4*)(&ldsB[ldso1]) = pf1;
                *(uint4*)(&ldsB[ldso2]) = pf2;
                __syncthreads();
                // ---- A fragments (per-lane) — issue first, on critical path ----
                short8 aMh = zero8, aMl = zero8, aSh = zero8, aSl = zero8;
                if (tv) {
                    aMh = *(const short8*)(aMhp + ab + kb);
                    aMl = *(const short8*)(aMlp + ab + kb);
                    aSh = *(const short8*)(aShp + ab + kb);
                    aSl = *(const short8*)(aSlp + ab + kb);
                    // ---- q9 accumulation from the loaded fragments ----
#pragma unroll
                    for (int e = 0; e < 8; e++) {
                        float m = bfval((unsigned short)aMh[e]) + bfval((unsigned short)aMl[e]);
                        qacc += m * m
                              + bfval((unsigned short)aSh[e]) + bfval((unsigned short)aSl[e]);
                    }
                }
                // ---- prefetch NEXT chunk's weight tile (latency hides under MFMA) ----
                {
                    int ncol = cofs + kb + 32;
                    size_t nbase;
                    bool hn;
                    if (ncol < Cin) { nbase = tapbase + ncol; hn = true; }
                    else            { nbase = tapbase + tapstep; hn = (tap < 8); }
                    if (hn) {
                        pf0 = *(const uint4*)(wsel0 + nbase + tofs0);
                        pf1 = *(const uint4*)(wsel1 + nbase + tofs1);
                        pf2 = *(const uint4*)(wsel2 + nbase + tofs2);
                    }
                }
#pragma unroll
                for (int nt = 0; nt < 4; nt++) {
                    int lo = (nt * 16 + row) * 36 + quad * 8;
                    short8 bh = *(const short8*)(&ldsB[lo]);
                    short8 bl = *(const short8*)(&ldsB[2304 + lo]);
                    short8 bq = *(const short8*)(&ldsB[4608 + lo]);
                    accM[nt] = __builtin_amdgcn_mfma_f32_16x16x32_bf16(aMh, bh, accM[nt], 0, 0, 0);
                    accM[nt] = __builtin_amdgcn_mfma_f32_16x16x32_bf16(aMl, bh, accM[nt], 0, 0, 0);
                    accM[nt] = __builtin_amdgcn_mfma_f32_16x16x32_bf16(aMh, bl, accM[nt], 0, 0, 0);
                    accM[nt] = __builtin_amdgcn_mfma_f32_16x16x32_bf16(aMl, bl, accM[nt], 0, 0, 0);
                    accS[nt] = __builtin_amdgcn_mfma_f32_16x16x32_bf16(aSh, bq, accS[nt], 0, 0, 0);
                    accS[nt] = __builtin_amdgcn_mfma_f32_16x16x32_bf16(aSl, bq, accS[nt], 0, 0, 0);
                }
            }
        }
    }

    // ---- finish q9: reduce across the 4 quads (lanes row, row+16, +32, +48) ----
    qacc += __shfl_xor(qacc, 16);
    qacc += __shfl_xor(qacc, 32);
    // every lane now holds q9 for pixel pixBase + (lane & 15)

#pragma unroll
    for (int nt = 0; nt < 4; nt++) {
        int co = coBase + nt * 16 + row;
        float spv = spv_[co];
        floatx4 am = accM[nt];
        floatx4 as = accS[nt];
#pragma unroll
        for (int r = 0; r < 4; r++) {
            int P2 = pixBase + quad * 4 + r;
            float qv = __shfl(qacc, quad * 4 + r);   // q9[P2] from lane quad*4+r
            if (P2 < total) {
                size_t o = (size_t)P2 * Cout + co;
                float mu = am[r];
                float s = qv * spv + as[r];
                if (!(mu > 0.f)) { mu = 0.f; s = 0.f; }
                if (oMf) oMf[o] = mu;
                if (oSf) oSf[o] = s;
                if (oMh) {
                    unsigned short mh = f2bf(mu);
                    oMh[o] = mh;
                    oMl[o] = f2bf(mu - bfval(mh));
                    unsigned short sh = f2bf(s);
                    oSh[o] = sh;
                    oSl[o] = f2bf(s - bfval(sh));
                }
            }
        }
    }
}

// ---- FUSED MFMA unpool layer, parity-classed: each block's 64 px share one
// (h&1, w&1) class, so tap validity is block-uniform and only the 1/2/2/4
// parity-valid taps run. Valid taps keep ascending order; skipped taps
// contributed exact +0 before -> per-pixel accumulation bitwise preserved.
// Weight tile staged directly global->reg->LDS per chunk (no prefetch;
// 4x fewer chunks). Output written via per-lane (img,h,w) decode.
__global__ void __launch_bounds__(256)
fused_unpool_kernel(const unsigned short* __restrict__ m1h, const unsigned short* __restrict__ m1l,
                    const unsigned short* __restrict__ s1h, const unsigned short* __restrict__ s1l,
                    const unsigned short* __restrict__ wTh, const unsigned short* __restrict__ wTl,
                    const unsigned short* __restrict__ wTsq,
                    const float* __restrict__ spv_,
                    unsigned short* __restrict__ oMh, unsigned short* __restrict__ oMl,
                    unsigned short* __restrict__ oSh, unsigned short* __restrict__ oSl,
                    int B_, int H, int W, int Hin, int Win,
                    int Cin, int Cout)
{
    __shared__ unsigned short ldsB[3 * 2304];
    const int tid = threadIdx.x;
    const int lane = tid & 63;
    const int wave = tid >> 6;
    const int He = (H + 1) >> 1, Hd = H >> 1;
    const int We = (W + 1) >> 1, Wd = W >> 1;
    const int n00 = B_ * He * We, n01 = B_ * He * Wd;
    const int n10 = B_ * Hd * We, n11 = B_ * Hd * Wd;
    const int nb00 = (n00 + 63) >> 6, nb01 = (n01 + 63) >> 6;
    const int nb10 = (n10 + 63) >> 6, nb11 = (n11 + 63) >> 6;
    const int ntiles = Cout >> 6;
    const int nReal = (nb00 + nb01 + nb10 + nb11) * ntiles;
    const int chunk = (int)gridDim.x >> 3;
    int gid = ((int)blockIdx.x & 7) * chunk + ((int)blockIdx.x >> 3);
    if (gid >= nReal) return;                   // block-uniform: barrier-safe
    const int coTile = gid % ntiles;
    int bid = gid / ntiles;
    int hpar, wpar, classN, Wc, Hc;
    if (bid < nb00)                    { hpar = 0; wpar = 0; classN = n00; Hc = He; Wc = We; }
    else if (bid < nb00 + nb01)        { bid -= nb00; hpar = 0; wpar = 1; classN = n01; Hc = He; Wc = Wd; }
    else if (bid < nb00 + nb01 + nb10) { bid -= nb00 + nb01; hpar = 1; wpar = 0; classN = n10; Hc = Hd; Wc = We; }
    else                               { bid -= nb00 + nb01 + nb10; hpar = 1; wpar = 1; classN = n11; Hc = Hd; Wc = Wd; }
    const int coBase = coTile * 64;
    const int row = lane & 15;
    const int quad = lane >> 4;
    const int pixBase = bid * 64 + wave * 16;   // within class

    // ---- per-thread staging constants (same layout as dense) ----
    const unsigned short* wsel0; const unsigned short* wsel1; const unsigned short* wsel2;
    int tofs0, tofs1, tofs2, ldso0, ldso1, ldso2;
    {
        int u = tid * 3;
        int arr = u >> 8, rem = u & 255, co = rem >> 2, part = rem & 3;
        wsel0 = (arr == 0) ? wTh : (arr == 1) ? wTl : wTsq;
        tofs0 = co * Cin + part * 8;
        ldso0 = arr * 2304 + co * 36 + part * 8;
        u++;
        arr = u >> 8; rem = u & 255; co = rem >> 2; part = rem & 3;
        wsel1 = (arr == 0) ? wTh : (arr == 1) ? wTl : wTsq;
        tofs1 = co * Cin + part * 8;
        ldso1 = arr * 2304 + co * 36 + part * 8;
        u++;
        arr = u >> 8; rem = u & 255; co = rem >> 2; part = rem & 3;
        wsel2 = (arr == 0) ? wTh : (arr == 1) ? wTl : wTsq;
        tofs2 = co * Cin + part * 8;
        ldso2 = arr * 2304 + co * 36 + part * 8;
    }

    // ---- per-lane pixel decode (class-local index -> (img, h, w)) ----
    int gp = pixBase + row;
    bool pv = gp < classN;
    int gpc = pv ? gp : 0;
    int hw = Hc * Wc;
    int img = gpc / hw;
    int rr = gpc - img * hw;
    int hh = ((rr / Wc) << 1) + hpar;
    int ww = ((rr - (rr / Wc) * Wc) << 1) + wpar;

    floatx4 accM[4], accS[4];
#pragma unroll
    for (int i = 0; i < 4; i++) {
        accM[i] = (floatx4){0.f, 0.f, 0.f, 0.f};
        accS[i] = (floatx4){0.f, 0.f, 0.f, 0.f};
    }
    const short8 zero8 = {0, 0, 0, 0, 0, 0, 0, 0};
    float qacc = 0.f;

    const size_t tapstep = (size_t)Cout * Cin;
    const size_t cobase_off = (size_t)coBase * Cin;

    // parity-valid taps: kh in {1} if hpar==0 else {0,2}; same for kw.
#pragma unroll
    for (int a = 0; a < 2; a++) {
        if (a == 1 && hpar == 0) break;         // block-uniform
        int kh = hpar ? (a << 1) : 1;
#pragma unroll
        for (int b = 0; b < 2; b++) {
            if (b == 1 && wpar == 0) break;     // block-uniform
            int kw = wpar ? (b << 1) : 1;
            int tap = kh * 3 + kw;
            size_t tapbase = (size_t)tap * tapstep + cobase_off;
            int ih = (hh + kh - 1) >> 1;        // always in [0,Hin) for valid parity
            int iw = (ww + kw - 1) >> 1;
            size_t ab = ((size_t)(img * Hin + ih) * Win + iw) * (size_t)Cin + quad * 8;
            for (int kb = 0; kb < Cin; kb += 32) {
                __syncthreads();
                // ---- stage weight tile: global -> reg -> LDS ----
                uint4 w0 = *(const uint4*)(wsel0 + tapbase + kb + tofs0);
                uint4 w1 = *(const uint4*)(wsel1 + tapbase + kb + tofs1);
                uint4 w2 = *(const uint4*)(wsel2 + tapbase + kb + tofs2);
                *(uint4*)(&ldsB[ldso0]) = w0;
                *(uint4*)(&ldsB[ldso1]) = w1;
                *(uint4*)(&ldsB[ldso2]) = w2;
                __syncthreads();
                // ---- A fragments + q9 ----
                short8 aMh = zero8, aMl = zero8, aSh = zero8, aSl = zero8;
                if (pv) {
                    aMh = *(const short8*)(m1h + ab + kb);
                    aMl = *(const short8*)(m1l + ab + kb);
                    aSh = *(const short8*)(s1h + ab + kb);
                    aSl = *(const short8*)(s1l + ab + kb);
#pragma unroll
                    for (int e = 0; e < 8; e++) {
                        float m = bfval((unsigned short)aMh[e]) + bfval((unsigned short)aMl[e]);
                        qacc += m * m
                              + bfval((unsigned short)aSh[e]) + bfval((unsigned short)aSl[e]);
                    }
                }
#pragma unroll
                for (int nt = 0; nt < 4; nt++) {
                    int lo = (nt * 16 + row) * 36 + quad * 8;
                    short8 bh = *(const short8*)(&ldsB[lo]);
                    short8 bl = *(const short8*)(&ldsB[2304 + lo]);
                    short8 bq = *(const short8*)(&ldsB[4608 + lo]);
                    accM[nt] = __builtin_amdgcn_mfma_f32_16x16x32_bf16(aMh, bh, accM[nt], 0, 0, 0);
                    accM[nt] = __builtin_amdgcn_mfma_f32_16x16x32_bf16(aMl, bh, accM[nt], 0, 0, 0);
                    accM[nt] = __builtin_amdgcn_mfma_f32_16x16x32_bf16(aMh, bl, accM[nt], 0, 0, 0);
                    accM[nt] = __builtin_amdgcn_mfma_f32_16x16x32_bf16(aMl, bl, accM[nt], 0, 0, 0);
                    accS[nt] = __builtin_amdgcn_mfma_f32_16x16x32_bf16(aSh, bq, accS[nt], 0, 0, 0);
                    accS[nt] = __builtin_amdgcn_mfma_f32_16x16x32_bf16(aSl, bq, accS[nt], 0, 0, 0);
                }
            }
        }
    }

    // ---- q9 quad reduce ----
    qacc += __shfl_xor(qacc, 16);
    qacc += __shfl_xor(qacc, 32);

#pragma unroll
    for (int nt = 0; nt < 4; nt++) {
        int co = coBase + nt * 16 + row;
        float spv = spv_[co];
        floatx4 am = accM[nt];
        floatx4 as = accS[nt];
#pragma unroll
        for (int r = 0; r < 4; r++) {
            int gp2 = pixBase + quad * 4 + r;
            float qv = __shfl(qacc, quad * 4 + r);
            if (gp2 < classN) {
                int img2 = gp2 / hw;
                int rr2 = gp2 - img2 * hw;
                int h2 = ((rr2 / Wc) << 1) + hpar;
                int w2 = ((rr2 - (rr2 / Wc) * Wc) << 1) + wpar;
                size_t o = ((size_t)(img2 * H + h2) * W + w2) * Cout + co;
                float mu = am[r];
                float s = qv * spv + as[r];
                if (!(mu > 0.f)) { mu = 0.f; s = 0.f; }
                unsigned short mh = f2bf(mu);
                oMh[o] = mh;
                oMl[o] = f2bf(mu - bfval(mh));
                unsigned short sh = f2bf(s);
                oSh[o] = sh;
                oSl[o] = f2bf(s - bfval(sh));
            }
        }
    }
}

// ---- first layer (Cin=3): hi/lo outputs
__global__ void conv_input_relu_kernel(const float* __restrict__ x,
                                       const float* __restrict__ w_mu,
                                       const float* __restrict__ w_sig,
                                       unsigned short* __restrict__ m_h,
                                       unsigned short* __restrict__ m_l,
                                       unsigned short* __restrict__ s_h,
                                       unsigned short* __restrict__ s_l,
                                       int B_, int H, int W, int Cin, int Cout)
{
    int co = threadIdx.x;
    int pix = blockIdx.x * blockDim.y + threadIdx.y;
    int total = B_ * H * W;
    if (pix >= total) return;
    int b = pix / (H * W);
    int rem = pix % (H * W);
    int h = rem / W, w = rem % W;

    float mu = 0.f, q = 0.f;
    for (int kh = 0; kh < 3; kh++) {
        int ih = h + kh - 1;
        if (ih < 0 || ih >= H) continue;
        for (int kw = 0; kw < 3; kw++) {
            int iw = w + kw - 1;
            if (iw < 0 || iw >= W) continue;
            const float* xp = x + ((size_t)(b * H + ih) * W + iw) * Cin;
            const float* wp = w_mu + (size_t)((kh * 3 + kw) * Cin) * Cout + co;
            for (int ci = 0; ci < Cin; ci++) {
                float xv = xp[ci];
                mu += xv * wp[(size_t)ci * Cout];
                q += xv * xv;
            }
        }
    }
    float s = q * softplus_f(w_sig[co]);
    if (!(mu > 0.f)) { mu = 0.f; s = 0.f; }
    size_t oidx = (size_t)pix * Cout + co;
    unsigned short mh = f2bf(mu);
    m_h[oidx] = mh;
    m_l[oidx] = f2bf(mu - bfval(mh));
    unsigned short sh = f2bf(s);
    s_h[oidx] = sh;
    s_l[oidx] = f2bf(s - bfval(sh));
}

// ---- pool: fp32 mu for argmax; outputs hi/lo mu + gathered hi/lo s
__global__ void pool_kernel(const float* __restrict__ mu_in,
                            const unsigned short* __restrict__ s_h,
                            const unsigned short* __restrict__ s_l,
                            unsigned short* __restrict__ pm_h,
                            unsigned short* __restrict__ pm_l,
                            unsigned short* __restrict__ ps_h,
                            unsigned short* __restrict__ ps_l,
                            int B_, int H, int W, int C)
{
    int Ho = H / 2, Wo = W / 2;
    size_t total = (size_t)B_ * Ho * Wo * C;
    size_t idx = (size_t)blockIdx.x * blockDim.x + threadIdx.x;
    if (idx >= total) return;
    int c = idx % C;
    size_t t = idx / C;
    int w = t % Wo; t /= Wo;
    int h = t % Ho;
    int b = t / Ho;
    size_t i0 = ((size_t)(b * H + 2 * h) * W + 2 * w) * C + c;
    size_t rowStride = (size_t)W * C;
    float m00 = mu_in[i0], m01 = mu_in[i0 + C];
    float m10 = mu_in[i0 + rowStride], m11 = mu_in[i0 + rowStride + C];
    int best = 0; float bm = m00;
    if (m01 > bm) { bm = m01; best = 1; }
    if (m10 > bm) { bm = m10; best = 2; }
    if (m11 > bm) { bm = m11; best = 3; }
    size_t off = (size_t)(best >> 1) * rowStride + (size_t)(best & 1) * C;
    unsigned short mh = f2bf(bm);
    pm_h[idx] = mh;
    pm_l[idx] = f2bf(bm - bfval(mh));
    ps_h[idx] = s_h[i0 + off];
    ps_l[idx] = s_l[i0 + off];
}

// ---- final 1x1 conv_inter + C=2 softmax density prop (fp32 in)
__global__ void final_kernel(const float* __restrict__ mu_in,
                             const float* __restrict__ s_in,
                             const float* __restrict__ w_mu,
                             const float* __restrict__ w_sig,
                             float* __restrict__ out,
                             int B_, int H, int W, int Cin)
{
    int pix = blockIdx.x * blockDim.x + threadIdx.x;
    int total = B_ * H * W;
    if (pix >= total) return;
    const float* mp = mu_in + (size_t)pix * Cin;
    const float* sp = s_in + (size_t)pix * Cin;
    float mu0 = 0.f, mu1 = 0.f, s0a = 0.f, s1a = 0.f, q = 0.f;
    for (int ci = 0; ci < Cin; ci += 4) {
        float4 m = *(const float4*)(mp + ci);
        float4 s = *(const float4*)(sp + ci);
        float4 wa = *(const float4*)(w_mu + ci * 2);
        float4 wb = *(const float4*)(w_mu + ci * 2 + 4);
        mu0 += m.x * wa.x + m.y * wa.z + m.z * wb.x + m.w * wb.z;
        mu1 += m.x * wa.y + m.y * wa.w + m.z * wb.y + m.w * wb.w;
        s0a += s.x * (wa.x * wa.x) + s.y * (wa.z * wa.z) + s.z * (wb.x * wb.x) + s.w * (wb.z * wb.z);
        s1a += s.x * (wa.y * wa.y) + s.y * (wa.w * wa.w) + s.z * (wb.y * wb.y) + s.w * (wb.w * wb.w);
        q += m.x * m.x + s.x + m.y * m.y + s.y + m.z * m.z + s.z + m.w * m.w + s.w;
    }
    float s0 = q * softplus_f(w_sig[0]) + s0a;
    float s1 = q * softplus_f(w_sig[1]) + s1a;
    float mx = fmaxf(mu0, mu1);
    float e0 = expf(mu0 - mx), e1 = expf(mu1 - mx);
    float inv = 1.f / (e0 + e1);
    float p0 = e0 * inv, p1 = e1 * inv;
    float g00 = p0 - p0 * p0, g01 = -p0 * p1;
    float g10 = -p1 * p0,     g11 = p1 - p1 * p1;
    float so0 = g00 * g00 * s0 + g01 * g01 * s1;
    float so1 = g10 * g10 * s0 + g11 * g11 * s1;
    out[(size_t)pix * 2]     = p0;
    out[(size_t)pix * 2 + 1] = p1;
    size_t off = (size_t)total * 2;
    out[off + (size_t)pix * 2]     = so0;
    out[off + (size_t)pix * 2 + 1] = so1;
}

// ---------------------------------------------------------------------------

extern "C" void kernel_launch(void* const* d_in, const int* in_sizes, int n_in,
                              void* d_out, int out_size, void* d_ws, size_t ws_size,
                              hipStream_t stream)
{
    const float* x = (const float*)d_in[0];
    enum { E1A, E1B, E2A, E2B, BA, BB, D2U, D2A, D2B, D1U, D1A, D1B, FIN, NW };
    const float* wmu[NW];
    const float* wsig[NW];
    for (int i = 0; i < NW; i++) {
        wmu[i]  = (const float*)d_in[1 + 2 * i];
        wsig[i] = (const float*)d_in[2 + 2 * i];
    }

    const int B_ = 4;
    float* ws = (float*)d_ws;
    float* M0  = ws;                         // 4194304 fp32 mu scratch
    float* SF  = ws + 4194304;               // 4194304 fp32 s scratch
    float* spb = ws + 8519680;               // 2048
    unsigned short* us = (unsigned short*)(ws + 8521728);
    const size_t NB = 4194304;
    unsigned short* aMh = us;                // A set
    unsigned short* aMl = us + NB;
    unsigned short* aSh = us + 2 * NB;
    unsigned short* aSl = us + 3 * NB;
    unsigned short* bMh = us + 4 * NB;       // B set
    unsigned short* bMl = us + 5 * NB;
    unsigned short* bSh = us + 6 * NB;
    unsigned short* bSl = us + 7 * NB;
    unsigned short* e1Mh = us + 8 * NB;      // E1 skip
    unsigned short* e1Ml = us + 9 * NB;
    unsigned short* e1Sh = us + 10 * NB;
    unsigned short* e1Sl = us + 11 * NB;
    unsigned short* e2Mh = us + 12 * NB;     // E2 skip (2097152 each)
    unsigned short* e2Ml = e2Mh + 2097152;
    unsigned short* e2Sh = e2Ml + 2097152;
    unsigned short* e2Sl = e2Sh + 2097152;
    unsigned short* wTh  = e2Sl + 2097152;   // 2064384 each (11 layers)
    unsigned short* wTl  = wTh + 2064384;
    unsigned short* wTsq = wTl + 2064384;

    // all 11 conv layers on MFMA
    const int mlay[11]  = {E1B, E2A, E2B, BA, BB, D2U, D2A, D2B, D1U, D1A, D1B};
    const int mcin[11]  = {64, 64, 128, 128, 256, 256, 256, 128, 128, 128, 64};
    const int mcout[11] = {64, 128, 128, 256, 256, 128, 128, 128, 64, 64, 64};
    size_t woff[NW]; int spoff[NW];
    {
        WMeta meta;
        int wo = 0, so = 0;
        for (int i = 0; i < 11; i++) {
            int l = mlay[i];
            woff[l] = (size_t)wo; spoff[l] = so;
            meta.w[i] = wmu[l];
            meta.wsig[i] = wsig[l];
            meta.woff_[i] = wo;
            meta.spoff_[i] = so;
            meta.cin_[i] = mcin[i];
            meta.cout_[i] = mcout[i];
            wo += 9 * mcin[i] * mcout[i];
            so += mcout[i];
        }
        meta.nlayers = 11;
        meta.totalW = wo;        // 2064384
        meta.totalSp = so;       // 1344
        int n = wo + so;
        wprep_all_kernel<<<dim3((n + 255) / 256), dim3(256), 0, stream>>>(
            meta, wTh, wTl, wTsq, spb);
    }

    // dense fused MFMA layer (q9 computed in-kernel)
    auto flayer = [&](const unsigned short* i_mh, const unsigned short* i_ml,
                      const unsigned short* i_sh, const unsigned short* i_sl, int ci1,
                      const unsigned short* k_mh, const unsigned short* k_ml,
                      const unsigned short* k_sh, const unsigned short* k_sl,
                      int ci2, int h2, int w2, int dh, int dw,
                      int H, int W, int widx, int cout,
                      float* oMf, float* oSf,
                      unsigned short* oMh, unsigned short* oMl,
                      unsigned short* oSh, unsigned short* oSl) {
        int total = B_ * H * W;
        int nReal = ((total + 63) / 64) * (cout / 64);
        int G = ((nReal + 7) / 8) * 8;
        fused_layer_kernel<<<dim3(G), dim3(256), 0, stream>>>(
            i_mh, i_ml, i_sh, i_sl, k_mh, k_ml, k_sh, k_sl,
            wTh + woff[widx], wTl + woff[widx], wTsq + woff[widx], spb + spoff[widx],
            oMf, oSf, oMh, oMl, oSh, oSl,
            B_, H, W, H, W, 0, ci1, ci2, h2, w2, dh, dw, cout);
    };

    // unpool fused MFMA layer (parity-classed): [Hin,Win,ci] -> [2Hin-1,2Win-1,cout]
    auto ulayer = [&](const unsigned short* i_mh, const unsigned short* i_ml,
                      const unsigned short* i_sh, const unsigned short* i_sl, int ci,
                      int Hin, int Win, int widx, int cout,
                      unsigned short* oMh, unsigned short* oMl,
                      unsigned short* oSh, unsigned short* oSl) {
        int Hout = 2 * Hin - 1, Wout = 2 * Win - 1;
        int He = (Hout + 1) / 2, Hd = Hout / 2;
        int We = (Wout + 1) / 2, Wd = Wout / 2;
        int nb = (B_ * He * We + 63) / 64 + (B_ * He * Wd + 63) / 64
               + (B_ * Hd * We + 63) / 64 + (B_ * Hd * Wd + 63) / 64;
        int nReal = nb * (cout / 64);
        int G = ((nReal + 7) / 8) * 8;
        fused_unpool_kernel<<<dim3(G), dim3(256), 0, stream>>>(
            i_mh, i_ml, i_sh, i_sl,
            wTh + woff[widx], wTl + woff[widx], wTsq + woff[widx], spb + spoff[widx],
            oMh, oMl, oSh, oSl,
            B_, Hout, Wout, Hin, Win, ci, cout);
    };

    // ---- encoder level 1 ----
    {
        int totalPix = B_ * 128 * 128;
        conv_input_relu_kernel<<<dim3((totalPix + 3) / 4), dim3(64, 4), 0, stream>>>(
            x, wmu[E1A], wsig[E1A], aMh, aMl, aSh, aSl, B_, 128, 128, 3, 64);
    }
    // E1B: A -> E1 skip (hi/lo) + fp32 mu (M0) for pool argmax
    flayer(aMh, aMl, aSh, aSl, 64, nullptr, nullptr, nullptr, nullptr, 0, 0, 0, 0, 0,
           128, 128, E1B, 64, M0, nullptr, e1Mh, e1Ml, e1Sh, e1Sl);
    {
        size_t total = (size_t)B_ * 64 * 64 * 64;
        pool_kernel<<<dim3((total + 255) / 256), dim3(256), 0, stream>>>(
            M0, e1Sh, e1Sl, bMh, bMl, bSh, bSl, B_, 128, 128, 64);
    }
    // ---- encoder level 2 ----
    flayer(bMh, bMl, bSh, bSl, 64, nullptr, nullptr, nullptr, nullptr, 0, 0, 0, 0, 0,
           64, 64, E2A, 128, nullptr, nullptr, aMh, aMl, aSh, aSl);
    flayer(aMh, aMl, aSh, aSl, 128, nullptr, nullptr, nullptr, nullptr, 0, 0, 0, 0, 0,
           64, 64, E2B, 128, M0, nullptr, e2Mh, e2Ml, e2Sh, e2Sl);
    {
        size_t total = (size_t)B_ * 32 * 32 * 128;
        pool_kernel<<<dim3((total + 255) / 256), dim3(256), 0, stream>>>(
            M0, e2Sh, e2Sl, bMh, bMl, bSh, bSl, B_, 64, 64, 128);
    }
    // ---- bottleneck ----
    flayer(bMh, bMl, bSh, bSl, 128, nullptr, nullptr, nullptr, nullptr, 0, 0, 0, 0, 0,
           32, 32, BA, 256, nullptr, nullptr, aMh, aMl, aSh, aSl);
    flayer(aMh, aMl, aSh, aSl, 256, nullptr, nullptr, nullptr, nullptr, 0, 0, 0, 0, 0,
           32, 32, BB, 256, nullptr, nullptr, bMh, bMl, bSh, bSl);
    // ---- decoder level 2 (parity-classed unpool conv) ----
    ulayer(bMh, bMl, bSh, bSl, 256, 32, 32, D2U, 128, aMh, aMl, aSh, aSl);
    flayer(aMh, aMl, aSh, aSl, 128, e2Mh, e2Ml, e2Sh, e2Sl, 128, 64, 64, 0, 0,
           63, 63, D2A, 128, nullptr, nullptr, bMh, bMl, bSh, bSl);
    flayer(bMh, bMl, bSh, bSl, 128, nullptr, nullptr, nullptr, nullptr, 0, 0, 0, 0, 0,
           63, 63, D2B, 128, nullptr, nullptr, aMh, aMl, aSh, aSl);
    // ---- decoder level 1 (parity-classed unpool conv) ----
    ulayer(aMh, aMl, aSh, aSl, 128, 63, 63, D1U, 64, bMh, bMl, bSh, bSl);
    flayer(bMh, bMl, bSh, bSl, 64, e1Mh, e1Ml, e1Sh, e1Sl, 64, 128, 128, 1, 1,
           125, 125, D1A, 64, nullptr, nullptr, aMh, aMl, aSh, aSl);
    flayer(aMh, aMl, aSh, aSl, 64, nullptr, nullptr, nullptr, nullptr, 0, 0, 0, 0, 0,
           125, 125, D1B, 64, M0, SF, nullptr, nullptr, nullptr, nullptr);
    // ---- final 1x1 + softmax prop ----
    {
        int totalPix = B_ * 125 * 125;
        final_kernel<<<dim3((totalPix + 63) / 64), dim3(64), 0, stream>>>(
            M0, SF, wmu[FIN], wsig[FIN], (float*)d_out, B_, 125, 125, 64);
    }
}